// Round 16
// baseline (368.481 us; speedup 1.0000x reference)
//
#include <hip/hip_runtime.h>
#include <stdint.h>

#define N_H    128
#define N_INV  96
#define HS     132      // bf16 H-tile stride (128+4)
#define EPSF   134      // f32 epilogue stride
#define TILES  2
#define NBLK   256      // persistent blocks; LDS pins exactly 1 per CU
#define KS1    10
#define KS2    4
#define W1_BYTES 81920
#define W2_BYTES 32768
#define W_BYTES  (W1_BYTES + W2_BYTES)        // 114688
#define WBUF     4352
#define NWAVE  8
#define BIAS_OFF (W_BYTES + NWAVE * WBUF)     // 149504
#define SMEM_BYTES (BIAS_OFF + 2048)          // 151552

typedef __bf16 bf16x8 __attribute__((ext_vector_type(8)));
typedef float  f32x4  __attribute__((ext_vector_type(4)));

__device__ __forceinline__ unsigned short f2bf(float f) {
    union { float f; unsigned u; } v; v.f = f;
    unsigned u = v.u;
    u += 0x7FFFu + ((u >> 16) & 1u);   // RNE
    return (unsigned short)(u >> 16);
}

// Pack weights in MFMA-fragment order, W1 then W2 contiguous:
//   wpk[(ks*8+nt)*512 + lane*8 + j] = W[k=ks*32+(lane>>4)*8+j][n=nt*16+(lane&15)]
__global__ void prep_weights(const float* __restrict__ W1,
                             const float* __restrict__ W2,
                             unsigned short* __restrict__ w1p,
                             unsigned short* __restrict__ w2p) {
    int idx = blockIdx.x * blockDim.x + threadIdx.x;
    if (idx < KS1 * 8 * 64 * 8) {
        int j = idx & 7, lane = (idx >> 3) & 63, nt = (idx >> 9) & 7, ks = idx >> 12;
        int k = ks * 32 + (lane >> 4) * 8 + j;
        int n = nt * 16 + (lane & 15);
        w1p[idx] = f2bf(W1[(size_t)k * N_H + n]);
    } else {
        int r = idx - KS1 * 8 * 64 * 8;
        if (r < KS2 * 8 * 64 * 8) {
            int j = r & 7, lane = (r >> 3) & 63, nt = (r >> 9) & 7, ks = r >> 12;
            int k = ks * 32 + (lane >> 4) * 8 + j;
            int n = nt * 16 + (lane & 15);
            w2p[r] = f2bf(W2[(size_t)k * N_H + n]);
        }
    }
}

// node_invariant -> bf16 so each gather fragment is a single 16B load.
__global__ void prep_ninv(const float* __restrict__ ninv,
                          unsigned short* __restrict__ nb, int n4) {
    int i = blockIdx.x * blockDim.x + threadIdx.x;
    if (i < n4) {
        float4 v = ((const float4*)ninv)[i];
        ((ushort4*)nb)[i] = make_ushort4(f2bf(v.x), f2bf(v.y), f2bf(v.z), f2bf(v.w));
    }
}

// R12 structure (proven best, 263us) with ONE change: per-wave DYNAMIC work
// queue (32-edge units via global atomicAdd) instead of static block ranges.
// Converts per-block max-of-8-waves latency into global mean and removes the
// 12-vs-13-chunk tail. Pipeline depth unchanged: w0=current, w1,w2,w3
// prefetch slots map exactly onto R12's c+1,c+2,c+3 stages.
__global__ __launch_bounds__(512, 2)
void edge_mlp(const unsigned short* __restrict__ ninvb, const float* __restrict__ ef,
              const int* __restrict__ ei,
              const unsigned short* __restrict__ wpk,
              const float* __restrict__ b1g, const float* __restrict__ b2g,
              const float* __restrict__ gg, const float* __restrict__ btg,
              float* __restrict__ out, int E, unsigned* __restrict__ cnt) {
    extern __shared__ __align__(16) char smem[];

    const int tid  = threadIdx.x;
    const int wv   = tid >> 6;
    const int lane = tid & 63;
    const int lr   = lane & 15;
    const int lkg  = lane >> 4;
    const int lk   = lkg * 8;
    const int qr   = lkg * 4;

    // ---- stage 112KB weights + 2KB bias/ln params into LDS ----
    {
        const char* gsrc = (const char*)wpk;
        #pragma unroll
        for (int i = 0; i < 14; ++i) {
            int ch = wv * 14 + i;
            __builtin_amdgcn_global_load_lds(
                (const __attribute__((address_space(1))) void*)(gsrc + ch * 1024 + lane * 16),
                (__attribute__((address_space(3))) void*)(smem + ch * 1024),
                16, 0, 0);
        }
        if (wv == 0) {
            const float* srcs[4] = { b1g, b2g, gg, btg };
            #pragma unroll
            for (int a = 0; a < 4; ++a) {
                #pragma unroll
                for (int h = 0; h < 2; ++h) {
                    __builtin_amdgcn_global_load_lds(
                        (const __attribute__((address_space(1))) void*)(srcs[a] + h * 64 + lane),
                        (__attribute__((address_space(3))) void*)(smem + BIAS_OFF + a * 512 + h * 256),
                        4, 0, 0);
                }
            }
        }
    }

    const float* b1l = (const float*)(smem + BIAS_OFF);
    const float* b2l = (const float*)(smem + BIAS_OFF + 512);
    const float* gl  = (const float*)(smem + BIAS_OFF + 1024);
    const float* btl = (const float*)(smem + BIAS_OFF + 1536);

    // ---- dynamic work queue: one 32-edge unit per grab ----
    int w0, w1, w2, w3;
    {
        int v = 0;
        if (lane == 0) v = (int)atomicAdd(cnt, 3u);
        v = __shfl(v, 0);
        w0 = v; w1 = v + 1; w2 = v + 2;   // 3 units grabbed at once (pipeline fill)
    }

    // ---- per-wave prologue: w0 gathers/ef; ei for w1, w2 ----
    bf16x8 an[TILES][6];
    f32x4  efa[TILES][4][2];
    int sA[TILES], dA[TILES], eS[TILES], eD[TILES];
    {
        #pragma unroll
        for (int t = 0; t < TILES; ++t) {
            int er = w0 * 32 + t * 16 + lr;
            int ee = er < E ? er : E - 1;
            int s0 = ei[ee], d0 = ei[(size_t)E + ee];
            #pragma unroll
            for (int q = 0; q < 6; ++q) {
                int row = q < 3 ? s0 : d0;
                an[t][q] = *(const bf16x8*)(ninvb + (size_t)row * N_INV + (q % 3) * 32 + lk);
            }
            const float* ap = ef + (size_t)ee * N_H;
            #pragma unroll
            for (int j = 0; j < 4; ++j) {
                efa[t][j][0] = *(const f32x4*)(ap + j * 32 + lk);
                efa[t][j][1] = *(const f32x4*)(ap + j * 32 + lk + 4);
            }
        }
        #pragma unroll
        for (int t = 0; t < TILES; ++t) {
            int er = w1 * 32 + t * 16 + lr;
            int ee = er < E ? er : E - 1;
            sA[t] = ei[ee]; dA[t] = ei[(size_t)E + ee];
        }
        #pragma unroll
        for (int t = 0; t < TILES; ++t) {
            int er = w2 * 32 + t * 16 + lr;
            int ee = er < E ? er : E - 1;
            eS[t] = ei[ee]; eD[t] = ei[(size_t)E + ee];
        }
    }

    __syncthreads();   // the only block-wide barrier

    char* buf = smem + W_BYTES + wv * WBUF;
    __bf16* hb = (__bf16*)buf;
    float* ep = (float*)buf;

    while (w0 * 32 < E) {
        // ---- GEMM1(w0): A from regs (gathers + inline-converted ef), B from LDS ----
        f32x4 acc[TILES][8] = {};
        #pragma unroll
        for (int ks = 0; ks < KS1; ++ks) {
            bf16x8 bfr[8];
            #pragma unroll
            for (int nt = 0; nt < 8; ++nt)
                bfr[nt] = *(const bf16x8*)(smem + ((ks * 8 + nt) << 10) + (lane << 4));
            #pragma unroll
            for (int t = 0; t < TILES; ++t) {
                bf16x8 a;
                if (ks < 6) {
                    a = an[t][ks];
                } else {
                    const int j = ks - 6;
                    union { __bf16 e[8]; bf16x8 v; } ua;
                    #pragma unroll
                    for (int m = 0; m < 4; ++m) {
                        ua.e[m]     = (__bf16)efa[t][j][0][m];
                        ua.e[4 + m] = (__bf16)efa[t][j][1][m];
                    }
                    a = ua.v;
                }
                __builtin_amdgcn_s_setprio(1);
                #pragma unroll
                for (int nt = 0; nt < 8; ++nt)
                    acc[t][nt] = __builtin_amdgcn_mfma_f32_16x16x32_bf16(a, bfr[nt], acc[t][nt], 0, 0, 0);
                __builtin_amdgcn_s_setprio(0);
            }
        }

        const int eb = w0 * 32;

        #pragma unroll
        for (int t = 0; t < TILES; ++t) {
            // ---- bias + ReLU -> bf16 H tile ----
            #pragma unroll
            for (int nt = 0; nt < 8; ++nt) {
                float bb = b1l[nt * 16 + lr];
                #pragma unroll
                for (int i = 0; i < 4; ++i) {
                    float v = acc[t][nt][i] + bb;
                    v = v > 0.0f ? v : 0.0f;
                    hb[(qr + i) * HS + nt * 16 + lr] = (__bf16)v;
                }
            }
            __builtin_amdgcn_wave_barrier();

            // ---- residual loads; GEMM2 hides their latency ----
            f32x4 res[2][4];
            #pragma unroll
            for (int h = 0; h < 2; ++h) {
                #pragma unroll
                for (int it = 0; it < 4; ++it) {
                    int cid = it * 64 + lane;
                    int row = cid >> 5, c4 = (cid & 31) << 2;
                    int erow = eb + t * 16 + 8 * h + row;
                    int ec = erow < E ? erow : E - 1;
                    res[h][it] = *(const f32x4*)(ef + (size_t)ec * N_H + c4);
                }
            }

            // ---- GEMM2: all-LDS ----
            f32x4 acc2[8] = {};
            #pragma unroll
            for (int ks = 0; ks < KS2; ++ks) {
                bf16x8 a = *(const bf16x8*)((const char*)hb + lr * (HS * 2) + ks * 64 + lkg * 16);
                __builtin_amdgcn_s_setprio(1);
                #pragma unroll
                for (int nt = 0; nt < 8; ++nt) {
                    bf16x8 w = *(const bf16x8*)(smem + W1_BYTES + ((ks * 8 + nt) << 10) + (lane << 4));
                    acc2[nt] = __builtin_amdgcn_mfma_f32_16x16x32_bf16(a, w, acc2[nt], 0, 0, 0);
                }
                __builtin_amdgcn_s_setprio(0);
            }

            if (t == 0) {
                // ---- issue gathers(w1) using sA/dA ----
                #pragma unroll
                for (int tt = 0; tt < TILES; ++tt) {
                    #pragma unroll
                    for (int q = 0; q < 6; ++q) {
                        int row = q < 3 ? sA[tt] : dA[tt];
                        an[tt][q] = *(const bf16x8*)(ninvb + (size_t)row * N_INV + (q % 3) * 32 + lk);
                    }
                }
                // rotate ei pipeline: sA <- eS (w2); grab w3; eS <- ei(w3)
                sA[0] = eS[0]; sA[1] = eS[1]; dA[0] = eD[0]; dA[1] = eD[1];
                {
                    int v = 0;
                    if (lane == 0) v = (int)atomicAdd(cnt, 1u);
                    w3 = __shfl(v, 0);
                }
                #pragma unroll
                for (int tt = 0; tt < TILES; ++tt) {
                    int er = w3 * 32 + tt * 16 + lr;
                    int ee = er < E ? er : E - 1;
                    eS[tt] = ei[ee]; eD[tt] = ei[(size_t)E + ee];
                }
            }

            // ---- bias + LayerNorm ----
            float s1[4] = {0.f, 0.f, 0.f, 0.f};
            float s2[4] = {0.f, 0.f, 0.f, 0.f};
            #pragma unroll
            for (int nt = 0; nt < 8; ++nt) {
                float bb = b2l[nt * 16 + lr];
                #pragma unroll
                for (int i = 0; i < 4; ++i) {
                    float v = acc2[nt][i] + bb;
                    acc2[nt][i] = v;
                    s1[i] += v;
                    s2[i] += v * v;
                }
            }
            #pragma unroll
            for (int m = 1; m < 16; m <<= 1) {
                #pragma unroll
                for (int i = 0; i < 4; ++i) {
                    s1[i] += __shfl_xor(s1[i], m);
                    s2[i] += __shfl_xor(s2[i], m);
                }
            }
            float mu[4], rs[4];
            #pragma unroll
            for (int i = 0; i < 4; ++i) {
                mu[i] = s1[i] * (1.0f / 128.0f);
                float var = s2[i] * (1.0f / 128.0f) - mu[i] * mu[i];
                rs[i] = rsqrtf(var + 1e-5f);
            }

            // ---- epilogue: two 8-row halves through the f32 LDS buffer ----
            #pragma unroll
            for (int h = 0; h < 2; ++h) {
                if ((lkg >> 1) == h) {
                    #pragma unroll
                    for (int nt = 0; nt < 8; ++nt) {
                        int cc = nt * 16 + lr;
                        float g  = gl[cc];
                        float bt = btl[cc];
                        #pragma unroll
                        for (int i = 0; i < 4; ++i)
                            ep[(qr - 8 * h + i) * EPSF + cc] = (acc2[nt][i] - mu[i]) * rs[i] * g + bt;
                    }
                }
                __builtin_amdgcn_wave_barrier();
                #pragma unroll
                for (int it = 0; it < 4; ++it) {
                    int cid = it * 64 + lane;
                    int row = cid >> 5, c4 = (cid & 31) << 2;
                    int erow = eb + t * 16 + 8 * h + row;
                    if (erow < E) {
                        f32x4 nv = *(const f32x4*)(ep + row * EPSF + c4);
                        *(f32x4*)(out + (size_t)erow * N_H + c4) = nv + res[h][it];
                    }
                }
                __builtin_amdgcn_wave_barrier();
            }
        }

        // ---- issue ef fragments (w1); GEMM1(w1) ks0-5 covers the latency ----
        {
            #pragma unroll
            for (int t = 0; t < TILES; ++t) {
                int er = w1 * 32 + t * 16 + lr;
                int ee = er < E ? er : E - 1;
                const float* ap = ef + (size_t)ee * N_H;
                #pragma unroll
                for (int j = 0; j < 4; ++j) {
                    efa[t][j][0] = *(const f32x4*)(ap + j * 32 + lk);
                    efa[t][j][1] = *(const f32x4*)(ap + j * 32 + lk + 4);
                }
            }
        }

        // rotate work ids
        w0 = w1; w1 = w2; w2 = w3;
    }
}

extern "C" void kernel_launch(void* const* d_in, const int* in_sizes, int n_in,
                              void* d_out, int out_size, void* d_ws, size_t ws_size,
                              hipStream_t stream) {
    const float* ninv = (const float*)d_in[0];
    const float* ef   = (const float*)d_in[1];
    const int*   ei   = (const int*)d_in[2];
    const float* W1   = (const float*)d_in[3];
    const float* b1   = (const float*)d_in[4];
    const float* W2   = (const float*)d_in[5];
    const float* b2   = (const float*)d_in[6];
    const float* g    = (const float*)d_in[7];
    const float* bt   = (const float*)d_in[8];
    float* out = (float*)d_out;

    const int E = in_sizes[1] / N_H;
    const int NNODE = in_sizes[0] / N_INV;

    unsigned short* w1p = (unsigned short*)d_ws;             // 40960 bf16
    unsigned short* w2p = w1p + KS1 * 8 * 64 * 8;            // 16384 bf16 (contiguous)
    unsigned short* nb  = w2p + KS2 * 8 * 64 * 8;            // NNODE*96 bf16
    unsigned* cnt = (unsigned*)((char*)d_ws + 114688 + (size_t)NNODE * N_INV * 2);

    hipFuncSetAttribute((const void*)edge_mlp,
                        hipFuncAttributeMaxDynamicSharedMemorySize, SMEM_BYTES);

    int prep_total = (KS1 + KS2) * 8 * 64 * 8;
    prep_weights<<<(prep_total + 255) / 256, 256, 0, stream>>>(W1, W2, w1p, w2p);

    int n4 = NNODE * N_INV / 4;
    prep_ninv<<<(n4 + 255) / 256, 256, 0, stream>>>(ninv, nb, n4);

    hipMemsetAsync(cnt, 0, 4, stream);   // zero the work-queue counter each call

    edge_mlp<<<NBLK, 512, SMEM_BYTES, stream>>>(nb, ef, ei, w1p, b1, b2, g, bt,
                                                out, E, cnt);
}

// Round 17
// 263.095 us; speedup vs baseline: 1.4006x; 1.4006x over previous
//
#include <hip/hip_runtime.h>
#include <stdint.h>

#define N_H    128
#define N_INV  96
#define HS     132      // bf16 H-tile stride (128+4)
#define EPSF   134      // f32 epilogue stride
#define TILES  2
#define NWAVE  8
#define CHUNK  256      // edges per chunk = 8 waves x 32
#define NBLK   256      // persistent blocks; LDS pins exactly 1 per CU
#define KS1    10
#define KS2    4
#define W1_BYTES 81920
#define W2_BYTES 32768
#define W_BYTES  (W1_BYTES + W2_BYTES)        // 114688
#define WBUF     4352
#define BIAS_OFF (W_BYTES + NWAVE * WBUF)     // 149504
#define SMEM_BYTES (BIAS_OFF + 2048)          // 151552

typedef __bf16 bf16x8 __attribute__((ext_vector_type(8)));
typedef float  f32x4  __attribute__((ext_vector_type(4)));

__device__ __forceinline__ unsigned short f2bf(float f) {
    union { float f; unsigned u; } v; v.f = f;
    unsigned u = v.u;
    u += 0x7FFFu + ((u >> 16) & 1u);   // RNE
    return (unsigned short)(u >> 16);
}

// Pack weights in MFMA-fragment order, W1 then W2 contiguous:
//   wpk[(ks*8+nt)*512 + lane*8 + j] = W[k=ks*32+(lane>>4)*8+j][n=nt*16+(lane&15)]
__global__ void prep_weights(const float* __restrict__ W1,
                             const float* __restrict__ W2,
                             unsigned short* __restrict__ w1p,
                             unsigned short* __restrict__ w2p) {
    int idx = blockIdx.x * blockDim.x + threadIdx.x;
    if (idx < KS1 * 8 * 64 * 8) {
        int j = idx & 7, lane = (idx >> 3) & 63, nt = (idx >> 9) & 7, ks = idx >> 12;
        int k = ks * 32 + (lane >> 4) * 8 + j;
        int n = nt * 16 + (lane & 15);
        w1p[idx] = f2bf(W1[(size_t)k * N_H + n]);
    } else {
        int r = idx - KS1 * 8 * 64 * 8;
        if (r < KS2 * 8 * 64 * 8) {
            int j = r & 7, lane = (r >> 3) & 63, nt = (r >> 9) & 7, ks = r >> 12;
            int k = ks * 32 + (lane >> 4) * 8 + j;
            int n = nt * 16 + (lane & 15);
            w2p[r] = f2bf(W2[(size_t)k * N_H + n]);
        }
    }
}

// node_invariant -> bf16 so each gather fragment is a single 16B load.
__global__ void prep_ninv(const float* __restrict__ ninv,
                          unsigned short* __restrict__ nb, int n4) {
    int i = blockIdx.x * blockDim.x + threadIdx.x;
    if (i < n4) {
        float4 v = ((const float4*)ninv)[i];
        ((ushort4*)nb)[i] = make_ushort4(f2bf(v.x), f2bf(v.y), f2bf(v.z), f2bf(v.w));
    }
}

// FINAL (R12 revert, proven 263.6us best of 16 rounds): persistent 256 blocks
// (1/CU, LDS-pinned), 112KB weights staged to LDS once via global_load_lds,
// barrier-free per-wave chunk loop with loop-carried prefetch (ei 2 chunks
// ahead, gathers/ef 1 chunk ahead, residual under GEMM2), s_setprio around
// MFMA bursts, native bf16 casts. Directions measured worse: batch-all-loads
// (R9), held-reg prefetch (R11 spill), 4 waves/SIMD (R13 spill), TILES=1 +
// 3 waves/SIMD (R14), residual-from-regs (R15 spill), dynamic queue (R16).
__global__ __launch_bounds__(512, 2)
void edge_mlp(const unsigned short* __restrict__ ninvb, const float* __restrict__ ef,
              const int* __restrict__ ei,
              const unsigned short* __restrict__ wpk,
              const float* __restrict__ b1g, const float* __restrict__ b2g,
              const float* __restrict__ gg, const float* __restrict__ btg,
              float* __restrict__ out, int E, int cbase, int crem) {
    extern __shared__ __align__(16) char smem[];

    const int tid  = threadIdx.x;
    const int wv   = tid >> 6;
    const int lane = tid & 63;
    const int lr   = lane & 15;
    const int lkg  = lane >> 4;
    const int lk   = lkg * 8;
    const int qr   = lkg * 4;

    const int b     = blockIdx.x;
    const int c0    = b * cbase + (b < crem ? b : crem);
    const int cnt   = cbase + (b < crem ? 1 : 0);
    if (cnt <= 0) return;
    const int clast = c0 + cnt - 1;

    // ---- stage 112KB weights + 2KB bias/ln params into LDS ----
    {
        const char* gsrc = (const char*)wpk;
        #pragma unroll
        for (int i = 0; i < 14; ++i) {
            int ch = wv * 14 + i;
            __builtin_amdgcn_global_load_lds(
                (const __attribute__((address_space(1))) void*)(gsrc + ch * 1024 + lane * 16),
                (__attribute__((address_space(3))) void*)(smem + ch * 1024),
                16, 0, 0);
        }
        if (wv == 0) {
            const float* srcs[4] = { b1g, b2g, gg, btg };
            #pragma unroll
            for (int a = 0; a < 4; ++a) {
                #pragma unroll
                for (int h = 0; h < 2; ++h) {
                    __builtin_amdgcn_global_load_lds(
                        (const __attribute__((address_space(1))) void*)(srcs[a] + h * 64 + lane),
                        (__attribute__((address_space(3))) void*)(smem + BIAS_OFF + a * 512 + h * 256),
                        4, 0, 0);
                }
            }
        }
    }

    const float* b1l = (const float*)(smem + BIAS_OFF);
    const float* b2l = (const float*)(smem + BIAS_OFF + 512);
    const float* gl  = (const float*)(smem + BIAS_OFF + 1024);
    const float* btl = (const float*)(smem + BIAS_OFF + 1536);

    // ---- per-wave prologue: chunk c0 gathers/ef; ei for c0+1, c0+2 ----
    bf16x8 an[TILES][6];
    f32x4  efa[TILES][4][2];
    int sA[TILES], dA[TILES], eS[TILES], eD[TILES];
    {
        #pragma unroll
        for (int t = 0; t < TILES; ++t) {
            int er = c0 * CHUNK + wv * 32 + t * 16 + lr;
            int ee = er < E ? er : E - 1;
            int s0 = ei[ee], d0 = ei[(size_t)E + ee];
            #pragma unroll
            for (int q = 0; q < 6; ++q) {
                int row = q < 3 ? s0 : d0;
                an[t][q] = *(const bf16x8*)(ninvb + (size_t)row * N_INV + (q % 3) * 32 + lk);
            }
            const float* ap = ef + (size_t)ee * N_H;
            #pragma unroll
            for (int j = 0; j < 4; ++j) {
                efa[t][j][0] = *(const f32x4*)(ap + j * 32 + lk);
                efa[t][j][1] = *(const f32x4*)(ap + j * 32 + lk + 4);
            }
        }
        int c1 = c0 + 1 <= clast ? c0 + 1 : clast;
        #pragma unroll
        for (int t = 0; t < TILES; ++t) {
            int er = c1 * CHUNK + wv * 32 + t * 16 + lr;
            int ee = er < E ? er : E - 1;
            sA[t] = ei[ee]; dA[t] = ei[(size_t)E + ee];
        }
        int c2 = c0 + 2 <= clast ? c0 + 2 : clast;
        #pragma unroll
        for (int t = 0; t < TILES; ++t) {
            int er = c2 * CHUNK + wv * 32 + t * 16 + lr;
            int ee = er < E ? er : E - 1;
            eS[t] = ei[ee]; eD[t] = ei[(size_t)E + ee];
        }
    }

    __syncthreads();   // the only block-wide barrier

    char* buf = smem + W_BYTES + wv * WBUF;
    __bf16* hb = (__bf16*)buf;
    float* ep = (float*)buf;

    for (int c = c0; c <= clast; ++c) {
        // ---- GEMM1(c): A from regs (gathers + inline-converted ef), B from LDS ----
        f32x4 acc[TILES][8] = {};
        #pragma unroll
        for (int ks = 0; ks < KS1; ++ks) {
            bf16x8 bfr[8];
            #pragma unroll
            for (int nt = 0; nt < 8; ++nt)
                bfr[nt] = *(const bf16x8*)(smem + ((ks * 8 + nt) << 10) + (lane << 4));
            #pragma unroll
            for (int t = 0; t < TILES; ++t) {
                bf16x8 a;
                if (ks < 6) {
                    a = an[t][ks];
                } else {
                    const int j = ks - 6;
                    union { __bf16 e[8]; bf16x8 v; } ua;
                    #pragma unroll
                    for (int m = 0; m < 4; ++m) {
                        ua.e[m]     = (__bf16)efa[t][j][0][m];
                        ua.e[4 + m] = (__bf16)efa[t][j][1][m];
                    }
                    a = ua.v;
                }
                __builtin_amdgcn_s_setprio(1);
                #pragma unroll
                for (int nt = 0; nt < 8; ++nt)
                    acc[t][nt] = __builtin_amdgcn_mfma_f32_16x16x32_bf16(a, bfr[nt], acc[t][nt], 0, 0, 0);
                __builtin_amdgcn_s_setprio(0);
            }
        }

        const int eb = c * CHUNK + wv * 32;

        #pragma unroll
        for (int t = 0; t < TILES; ++t) {
            // ---- bias + ReLU -> bf16 H tile ----
            #pragma unroll
            for (int nt = 0; nt < 8; ++nt) {
                float bb = b1l[nt * 16 + lr];
                #pragma unroll
                for (int i = 0; i < 4; ++i) {
                    float v = acc[t][nt][i] + bb;
                    v = v > 0.0f ? v : 0.0f;
                    hb[(qr + i) * HS + nt * 16 + lr] = (__bf16)v;
                }
            }
            __builtin_amdgcn_wave_barrier();

            // ---- residual loads; GEMM2 hides their latency ----
            f32x4 res[2][4];
            #pragma unroll
            for (int h = 0; h < 2; ++h) {
                #pragma unroll
                for (int it = 0; it < 4; ++it) {
                    int cid = it * 64 + lane;
                    int row = cid >> 5, c4 = (cid & 31) << 2;
                    int erow = eb + t * 16 + 8 * h + row;
                    int ec = erow < E ? erow : E - 1;
                    res[h][it] = *(const f32x4*)(ef + (size_t)ec * N_H + c4);
                }
            }

            // ---- GEMM2: all-LDS ----
            f32x4 acc2[8] = {};
            #pragma unroll
            for (int ks = 0; ks < KS2; ++ks) {
                bf16x8 a = *(const bf16x8*)((const char*)hb + lr * (HS * 2) + ks * 64 + lkg * 16);
                __builtin_amdgcn_s_setprio(1);
                #pragma unroll
                for (int nt = 0; nt < 8; ++nt) {
                    bf16x8 w = *(const bf16x8*)(smem + W1_BYTES + ((ks * 8 + nt) << 10) + (lane << 4));
                    acc2[nt] = __builtin_amdgcn_mfma_f32_16x16x32_bf16(a, w, acc2[nt], 0, 0, 0);
                }
                __builtin_amdgcn_s_setprio(0);
            }

            if (t == 0) {
                // ---- issue gathers(c+1) using sA/dA (ei one ahead) ----
                #pragma unroll
                for (int tt = 0; tt < TILES; ++tt) {
                    #pragma unroll
                    for (int q = 0; q < 6; ++q) {
                        int row = q < 3 ? sA[tt] : dA[tt];
                        an[tt][q] = *(const bf16x8*)(ninvb + (size_t)row * N_INV + (q % 3) * 32 + lk);
                    }
                }
                // rotate ei pipeline: sA <- eS (chunk c+2); issue eS <- ei(c+3)
                sA[0] = eS[0]; sA[1] = eS[1]; dA[0] = eD[0]; dA[1] = eD[1];
                int c3 = c + 3 <= clast ? c + 3 : clast;
                #pragma unroll
                for (int tt = 0; tt < TILES; ++tt) {
                    int er = c3 * CHUNK + wv * 32 + tt * 16 + lr;
                    int ee = er < E ? er : E - 1;
                    eS[tt] = ei[ee]; eD[tt] = ei[(size_t)E + ee];
                }
            }

            // ---- bias + LayerNorm ----
            float s1[4] = {0.f, 0.f, 0.f, 0.f};
            float s2[4] = {0.f, 0.f, 0.f, 0.f};
            #pragma unroll
            for (int nt = 0; nt < 8; ++nt) {
                float bb = b2l[nt * 16 + lr];
                #pragma unroll
                for (int i = 0; i < 4; ++i) {
                    float v = acc2[nt][i] + bb;
                    acc2[nt][i] = v;
                    s1[i] += v;
                    s2[i] += v * v;
                }
            }
            #pragma unroll
            for (int m = 1; m < 16; m <<= 1) {
                #pragma unroll
                for (int i = 0; i < 4; ++i) {
                    s1[i] += __shfl_xor(s1[i], m);
                    s2[i] += __shfl_xor(s2[i], m);
                }
            }
            float mu[4], rs[4];
            #pragma unroll
            for (int i = 0; i < 4; ++i) {
                mu[i] = s1[i] * (1.0f / 128.0f);
                float var = s2[i] * (1.0f / 128.0f) - mu[i] * mu[i];
                rs[i] = rsqrtf(var + 1e-5f);
            }

            // ---- epilogue: two 8-row halves through the f32 LDS buffer ----
            #pragma unroll
            for (int h = 0; h < 2; ++h) {
                if ((lkg >> 1) == h) {
                    #pragma unroll
                    for (int nt = 0; nt < 8; ++nt) {
                        int cc = nt * 16 + lr;
                        float g  = gl[cc];
                        float bt = btl[cc];
                        #pragma unroll
                        for (int i = 0; i < 4; ++i)
                            ep[(qr - 8 * h + i) * EPSF + cc] = (acc2[nt][i] - mu[i]) * rs[i] * g + bt;
                    }
                }
                __builtin_amdgcn_wave_barrier();
                #pragma unroll
                for (int it = 0; it < 4; ++it) {
                    int cid = it * 64 + lane;
                    int row = cid >> 5, c4 = (cid & 31) << 2;
                    int erow = eb + t * 16 + 8 * h + row;
                    if (erow < E) {
                        f32x4 nv = *(const f32x4*)(ep + row * EPSF + c4);
                        *(f32x4*)(out + (size_t)erow * N_H + c4) = nv + res[h][it];
                    }
                }
                __builtin_amdgcn_wave_barrier();
            }
        }

        // ---- issue ef fragments (c+1); GEMM1(c+1) ks0-5 covers the latency ----
        {
            int cn = c + 1 <= clast ? c + 1 : clast;
            #pragma unroll
            for (int t = 0; t < TILES; ++t) {
                int er = cn * CHUNK + wv * 32 + t * 16 + lr;
                int ee = er < E ? er : E - 1;
                const float* ap = ef + (size_t)ee * N_H;
                #pragma unroll
                for (int j = 0; j < 4; ++j) {
                    efa[t][j][0] = *(const f32x4*)(ap + j * 32 + lk);
                    efa[t][j][1] = *(const f32x4*)(ap + j * 32 + lk + 4);
                }
            }
        }
    }
}

extern "C" void kernel_launch(void* const* d_in, const int* in_sizes, int n_in,
                              void* d_out, int out_size, void* d_ws, size_t ws_size,
                              hipStream_t stream) {
    const float* ninv = (const float*)d_in[0];
    const float* ef   = (const float*)d_in[1];
    const int*   ei   = (const int*)d_in[2];
    const float* W1   = (const float*)d_in[3];
    const float* b1   = (const float*)d_in[4];
    const float* W2   = (const float*)d_in[5];
    const float* b2   = (const float*)d_in[6];
    const float* g    = (const float*)d_in[7];
    const float* bt   = (const float*)d_in[8];
    float* out = (float*)d_out;

    const int E = in_sizes[1] / N_H;
    const int NNODE = in_sizes[0] / N_INV;

    unsigned short* w1p = (unsigned short*)d_ws;             // 40960 bf16
    unsigned short* w2p = w1p + KS1 * 8 * 64 * 8;            // 16384 bf16 (contiguous)
    unsigned short* nb  = w2p + KS2 * 8 * 64 * 8;            // NNODE*96 bf16

    hipFuncSetAttribute((const void*)edge_mlp,
                        hipFuncAttributeMaxDynamicSharedMemorySize, SMEM_BYTES);

    int prep_total = (KS1 + KS2) * 8 * 64 * 8;
    prep_weights<<<(prep_total + 255) / 256, 256, 0, stream>>>(W1, W2, w1p, w2p);

    int n4 = NNODE * N_INV / 4;
    prep_ninv<<<(n4 + 255) / 256, 256, 0, stream>>>(ninv, nb, n4);

    int nchunks = (E + CHUNK - 1) / CHUNK;
    int cbase = nchunks / NBLK;
    int crem  = nchunks - cbase * NBLK;
    edge_mlp<<<NBLK, 512, SMEM_BYTES, stream>>>(nb, ef, ei, w1p, b1, b2, g, bt,
                                                out, E, cbase, crem);
}